// Round 6
// baseline (663.157 us; speedup 1.0000x reference)
//
#include <hip/hip_runtime.h>

typedef __bf16 bf16;
typedef __bf16 bf16x4 __attribute__((ext_vector_type(4)));
typedef __bf16 bf16x8 __attribute__((ext_vector_type(8)));
typedef float  f32x4  __attribute__((ext_vector_type(4)));

#define BM 128
#define BN 128
#define BK 32

__device__ __forceinline__ void async_copy16(const void* g, void* l) {
    __builtin_amdgcn_global_load_lds(
        (__attribute__((address_space(1))) void*)(g),
        (__attribute__((address_space(3))) void*)(l),
        16, 0, 0);
}

// C[z,m,n] = f( alpha * sum_k A[z,m,k]*B[z,n,k] )  — NT GEMM, z-batched.
// 3-stage LDS pipeline: raw s_barrier + s_waitcnt vmcnt(8/4/0); prefetch for
// tiles k+1,k+2 stays in flight across the barrier (no full drain until the
// tail), unlike __syncthreads() which forces vmcnt(0).
// do_exp: epilogue computes unnormalized softmax numerator exp(alpha*acc)
//   (causal-masked), writes bf16, atomicAdds 128-col row partials into lsum.
// rs_recip: epilogue multiplies by 1/lsum[row] (PV normalization).
// qkv_mode: N spans 3 concatenated 1024-col outputs C0/C1/C2.
// rev_m: longest-work-first block order for triangular grids.
__global__ __launch_bounds__(256)
void gemm_nt(const bf16* __restrict__ A, int lda, size_t az,
             const bf16* __restrict__ B, int ldb, size_t bz,
             void* __restrict__ C0, void* __restrict__ C1, void* __restrict__ C2,
             int ldc, size_t cz,
             int M, int N, int K, float alpha,
             const float* __restrict__ bias,
             float* __restrict__ lsum, int lsz,
             int out_bf16, int qkv_mode, int causal_skip, int kcap,
             int row_off, int rev_m, int do_exp, int rs_recip)
{
    int z  = blockIdx.z;
    int by = rev_m ? (gridDim.y - 1 - blockIdx.y) : blockIdx.y;
    int m0 = by * BM;
    int n0 = blockIdx.x * BN;
    if (causal_skip && n0 > row_off + m0 + BM - 1) return;  // above diagonal
    int Keff = kcap ? min(K, row_off + m0 + BM) : K;        // >=128 always
    A += (size_t)z * az;
    B += (size_t)z * bz;

    __shared__ __attribute__((aligned(16))) bf16 As[3][BM * BK];  // 3 x 8 KB
    __shared__ __attribute__((aligned(16))) bf16 Bs[3][BN * BK];  // 3 x 8 KB

    int tid  = threadIdx.x;
    int lane = tid & 63;
    int q    = lane >> 4;    // 0..3  (k-group)
    int r    = lane & 15;    // 0..15 (row-in-16)
    int wave = tid >> 6;
    int wm   = (wave >> 1) * 64;
    int wn   = (wave & 1) * 64;
    int sw   = (r >> 1) & 3;                        // read-side swizzle
    int gsw  = ((tid & 3) ^ ((tid >> 3) & 3)) * 8;  // stage-side swizzle

    f32x4 acc[4][4];
#pragma unroll
    for (int i = 0; i < 4; i++)
#pragma unroll
        for (int j = 0; j < 4; j++) acc[i][j] = (f32x4){0.f, 0.f, 0.f, 0.f};

    const bf16* Ag = A + (size_t)(m0 + (tid >> 2)) * lda + gsw;
    const bf16* Bg = B + (size_t)(n0 + (tid >> 2)) * ldb + gsw;
    size_t astep = (size_t)64 * lda;
    size_t bstep = (size_t)64 * ldb;

    auto issue = [&](int kt, int bi) {
        const bf16* a = Ag + (size_t)kt * BK;
        const bf16* b = Bg + (size_t)kt * BK;
        char* la = (char*)(&As[bi][0]) + tid * 16;
        char* lb = (char*)(&Bs[bi][0]) + tid * 16;
        async_copy16(a,         la);
        async_copy16(a + astep, la + 4096);
        async_copy16(b,         lb);
        async_copy16(b + bstep, lb + 4096);
    };

    int n_it = Keff / BK;        // >= 4
    issue(0, 0);
    issue(1, 1);
    for (int k = 0; k < n_it; ++k) {
        int pf = k + 2;
        if (pf < n_it) {
            issue(pf, pf % 3);
            asm volatile("s_waitcnt vmcnt(8)" ::: "memory");  // tile k landed
        } else if (k + 1 < n_it) {
            asm volatile("s_waitcnt vmcnt(4)" ::: "memory");
        } else {
            asm volatile("s_waitcnt vmcnt(0)" ::: "memory");
        }
        asm volatile("s_barrier" ::: "memory");

        const bf16* as = &As[k % 3][0];
        const bf16* bs = &Bs[k % 3][0];
        bf16x8 av[4], bv[4];
#pragma unroll
        for (int mi = 0; mi < 4; mi++)
            av[mi] = *(const bf16x8*)&as[(wm + mi * 16 + r) * BK + (q ^ sw) * 8];
#pragma unroll
        for (int ni = 0; ni < 4; ni++)
            bv[ni] = *(const bf16x8*)&bs[(wn + ni * 16 + r) * BK + (q ^ sw) * 8];
#pragma unroll
        for (int mi = 0; mi < 4; mi++)
#pragma unroll
            for (int ni = 0; ni < 4; ni++)
                acc[mi][ni] = __builtin_amdgcn_mfma_f32_16x16x32_bf16(
                    av[mi], bv[ni], acc[mi][ni], 0, 0, 0);

        asm volatile("s_waitcnt lgkmcnt(0)" ::: "memory");  // reads done
        asm volatile("s_barrier" ::: "memory");             // buf reusable
    }

    void* Cb = C0;
    if (qkv_mode) { int sel = n0 >> 10; Cb = sel == 0 ? C0 : (sel == 1 ? C1 : C2); }
    // epilogue: C/D layout col=lane&15, row=(lane>>4)*4+j  (m89-verified)
    if (do_exp) {
        // unnormalized causal softmax numerator + atomic row sums
        float* lz = lsum + (size_t)z * lsz;
        bf16*  Cz = (bf16*)Cb + (size_t)z * cz;
#pragma unroll
        for (int mi = 0; mi < 4; mi++) {
#pragma unroll
            for (int j = 0; j < 4; j++) {
                int row  = m0 + wm + mi * 16 + q * 4 + j;
                int grow = row + row_off;
                float rsum = 0.f;
#pragma unroll
                for (int ni = 0; ni < 4; ni++) {
                    int col = n0 + wn + ni * 16 + r;
                    float e = (col <= grow) ? __expf(acc[mi][ni][j] * alpha) : 0.f;
                    rsum += e;
                    Cz[(size_t)row * ldc + col] = (bf16)e;
                }
                rsum += __shfl_xor(rsum, 1, 64);
                rsum += __shfl_xor(rsum, 2, 64);
                rsum += __shfl_xor(rsum, 4, 64);
                rsum += __shfl_xor(rsum, 8, 64);
                if (r == 0) atomicAdd(&lz[row], rsum);
            }
        }
    } else {
        const float* lz = lsum ? lsum + (size_t)z * lsz : nullptr;
#pragma unroll
        for (int mi = 0; mi < 4; mi++) {
#pragma unroll
            for (int ni = 0; ni < 4; ni++) {
#pragma unroll
                for (int j = 0; j < 4; j++) {
                    int row = m0 + wm + mi * 16 + q * 4 + j;
                    int col = n0 + wn + ni * 16 + r;
                    if (qkv_mode) col &= 1023;
                    float v = acc[mi][ni][j] * alpha;
                    if (rs_recip) v *= 1.0f / lz[row];
                    if (bias)     v += bias[col];
                    if (out_bf16) ((bf16*)Cb + (size_t)z * cz)[(size_t)row * ldc + col] = (bf16)v;
                    else          ((float*)Cb + (size_t)z * cz)[(size_t)row * ldc + col] = v;
                }
            }
        }
    }
}

// batched transpose: V (B,T,C) -> VT (B,C,T), bf16
__global__ __launch_bounds__(256)
void transpose64(const bf16* __restrict__ V, bf16* __restrict__ VT, int T, int C)
{
    __shared__ bf16 tile[64][65];
    int b  = blockIdx.z;
    int s0 = blockIdx.x * 64, d0 = blockIdx.y * 64;
    const bf16* Vb  = V  + (size_t)b * T * C;
    bf16*       VTb = VT + (size_t)b * T * C;
    int tx = threadIdx.x & 63, ty = threadIdx.x >> 6;
#pragma unroll
    for (int i = 0; i < 64; i += 4)
        tile[ty + i][tx] = Vb[(size_t)(s0 + ty + i) * C + d0 + tx];
    __syncthreads();
#pragma unroll
    for (int i = 0; i < 64; i += 4)
        VTb[(size_t)(d0 + ty + i) * T + s0 + tx] = tile[tx][ty + i];
}

__global__ void cvt_f32_bf16(const float4* __restrict__ in, bf16x4* __restrict__ out, int n4)
{
    int i = blockIdx.x * blockDim.x + threadIdx.x;
    int stride = gridDim.x * blockDim.x;
    for (; i < n4; i += stride) {
        float4 v = in[i];
        bf16x4 o = { (bf16)v.x, (bf16)v.y, (bf16)v.z, (bf16)v.w };
        out[i] = o;
    }
}

extern "C" void kernel_launch(void* const* d_in, const int* in_sizes, int n_in,
                              void* d_out, int out_size, void* d_ws, size_t ws_size,
                              hipStream_t stream)
{
    const int B = 4, T = 4096, C = 1024, M = B * T;
    const float* x  = (const float*)d_in[0];
    const float* Wq = (const float*)d_in[1];
    const float* Wk = (const float*)d_in[2];
    const float* Wv = (const float*)d_in[3];
    const float* Wo = (const float*)d_in[4];
    const float* bo = (const float*)d_in[5];
    float* out = (float*)d_out;

    char* ws = (char*)d_ws;
    size_t off = 0;
    auto alloc = [&](size_t bytes) -> char* {
        char* p = ws + off;
        off += (bytes + 255) & ~(size_t)255;
        return p;
    };
    bf16* Wcat = (bf16*)alloc((size_t)3 * C * C * 2);  // [Wq; Wk; Wv]
    bf16* Wob  = (bf16*)alloc((size_t)C * C * 2);
    bf16* Qb   = (bf16*)alloc((size_t)M * C * 2);
    bf16* Kb   = (bf16*)alloc((size_t)M * C * 2);
    bf16* VT   = (bf16*)alloc((size_t)M * C * 2);

    // Preferred plan (chunk = T, ~232 MB — ws proven >= 235 MB in round 1):
    //   S region hosts xb and raw-V during projection (dead before S written);
    //   attention output O aliases Qb (Q dead after the single S-GEMM).
    size_t base = off;
    int chunk = T;
    bf16 *S, *xb, *Vtmp, *Ob;
    float* lsum;
    {
        size_t need = base + (((size_t)B * T * T * 2 + 255) & ~(size_t)255)
                           + (((size_t)B * T * 4 + 255) & ~(size_t)255);
        if (need <= ws_size) {
            S    = (bf16*)alloc((size_t)B * T * T * 2);
            lsum = (float*)alloc((size_t)B * T * 4);
            xb   = S;
            Vtmp = S + (size_t)M * C;   // 32 MB past xb, inside S region
            Ob   = Qb;                  // O overwrites Q after S-GEMM
        } else {
            Ob = (bf16*)alloc((size_t)M * C * 2);
            chunk = T / 2;
            while (chunk > 1024) {
                size_t nd = off + (((size_t)B * chunk * T * 2 + 255) & ~(size_t)255)
                                + (((size_t)B * chunk * 4 + 255) & ~(size_t)255);
                if (nd <= ws_size) break;
                chunk >>= 1;
            }
            S    = (bf16*)alloc((size_t)B * chunk * T * 2);
            lsum = (float*)alloc((size_t)B * chunk * 4);
            xb   = S;   // x dead after QKV projection
            Vtmp = Ob;  // V staged in Ob, transposed before PV writes Ob
        }
    }

    dim3 blk(256);

    cvt_f32_bf16<<<dim3(4096), blk, 0, stream>>>((const float4*)x,  (bf16x4*)xb, M * C / 4);
    cvt_f32_bf16<<<dim3(1024), blk, 0, stream>>>((const float4*)Wq, (bf16x4*)(Wcat),             C * C / 4);
    cvt_f32_bf16<<<dim3(1024), blk, 0, stream>>>((const float4*)Wk, (bf16x4*)(Wcat + C * C),     C * C / 4);
    cvt_f32_bf16<<<dim3(1024), blk, 0, stream>>>((const float4*)Wv, (bf16x4*)(Wcat + 2 * C * C), C * C / 4);
    cvt_f32_bf16<<<dim3(1024), blk, 0, stream>>>((const float4*)Wo, (bf16x4*)Wob, C * C / 4);

    // fused QKV projection: [Q|K|V] = X * Wcat^T
    gemm_nt<<<dim3(3 * C / BN, M / BM, 1), blk, 0, stream>>>(
        xb, C, 0, Wcat, C, 0, Qb, Kb, Vtmp, C, 0, M, 3 * C, C, 1.f,
        nullptr, nullptr, 0, 1, 1, 0, 0, 0, 0, 0, 0);
    transpose64<<<dim3(T / 64, C / 64, B), blk, 0, stream>>>(Vtmp, VT, T, C);

    const float scale = 0.03125f;  // 1/sqrt(1024)
    for (int toff = 0; toff < T; toff += chunk) {
        hipMemsetAsync(lsum, 0, (size_t)B * chunk * 4, stream);
        // S = exp(Q_chunk * K^T * scale) unnormalized, causal; row sums -> lsum
        gemm_nt<<<dim3(T / BN, chunk / BM, B), blk, 0, stream>>>(
            Qb + (size_t)toff * C, C, (size_t)T * C,
            Kb, C, (size_t)T * C,
            S, nullptr, nullptr, T, (size_t)chunk * T,
            chunk, T, C, scale,
            nullptr, lsum, chunk, 1, 0, 1, 0, toff, 1, 1, 0);
        // O = (P * V) / l   (NT vs VT, K capped at diagonal, longest-m first)
        gemm_nt<<<dim3(C / BN, chunk / BM, B), blk, 0, stream>>>(
            S, T, (size_t)chunk * T,
            VT, T, (size_t)T * C,
            Ob + (size_t)toff * C, nullptr, nullptr, C, (size_t)T * C,
            chunk, C, T, 1.f,
            nullptr, lsum, chunk, 1, 0, 0, 1, toff, 1, 0, 1);
    }

    // Y = O * Wo^T + bo  (fp32 out)
    gemm_nt<<<dim3(C / BN, M / BM, 1), blk, 0, stream>>>(
        Ob, C, 0, Wob, C, 0, out, nullptr, nullptr, C, 0, M, C, C, 1.f,
        bo, nullptr, 0, 0, 0, 0, 0, 0, 0, 0, 0);
}